// Round 10
// baseline (225.957 us; speedup 1.0000x reference)
//
#include <hip/hip_runtime.h>
#include <stdint.h>

#define NN 50000
#define NE 800000
#define NB 196     // scan blocks over nodes
#define NBK 196    // edge chunks
#define NBUK 196   // dst buckets of 256 nodes
#define CHK 4096   // edges per chunk
#define MTOT (NBUK * NBK)   // 38416
#define CVTB 6250  // cvt blocks: NN*128/4/256
#define PREPB 418  // prep blocks
// IN=128, HID=256, LAT=64

typedef __bf16 bf16x8 __attribute__((ext_vector_type(8)));
typedef float f32x4 __attribute__((ext_vector_type(4)));
typedef unsigned short ushort_t;
typedef unsigned short us4v __attribute__((ext_vector_type(4)));   // native vec for nt builtins
typedef float f4v __attribute__((ext_vector_type(4)));

__device__ inline float bf2f(uint16_t u) {
    union { uint32_t i; float f; } v; v.i = ((uint32_t)u) << 16; return v.f;
}
__device__ inline uint16_t f2bf(float f) {
    uint32_t u = __float_as_uint(f);
    u += 0x7fffu + ((u >> 16) & 1u);
    return (uint16_t)(u >> 16);
}
__device__ inline float rdf(const void* p, int i, int bf) {
    return bf ? bf2f(((const ushort_t*)p)[i]) : ((const float*)p)[i];
}

// ---------------- block-local mode detection ----------------
__device__ inline int blk_or(int v, int* flag) {
    if (threadIdx.x == 0) *flag = 0;
    __syncthreads();
    if (v) atomicOr(flag, 1);
    __syncthreads();
    return *flag;
}
// 1 => ei is int64 (index low words via <<1), 0 => int32
__device__ inline int detect_sh(const int* __restrict__ ei, int* flag) {
    int t = threadIdx.x;
    int v = ei[2 * t + 1] | ei[2 * (t + 256) + 1] | ei[2 * (t + 512) + 1] | ei[2 * (t + 768) + 1];
    return blk_or(v, flag) ? 0 : 1;
}
// 1 => x is bf16, 0 => f32
__device__ inline int detect_bf(const ushort_t* __restrict__ xw, int* flag) {
    int t = threadIdx.x;
    int bad = 0;
#pragma unroll
    for (int r = 0; r < 2; ++r) {
        uint16_t w = xw[t + 256 * r];
        int e = (w >> 7) & 0xFF;
        if (!(w == 0 || (e >= 96 && e <= 144))) bad = 1;
    }
    return blk_or(bad, flag) ? 0 : 1;
}

// ---------------- stage1: histA ∥ cvt ∥ prep3 in one grid ----------------
__global__ __launch_bounds__(256) void k_stage1(const int* __restrict__ ei, const void* __restrict__ x,
                                                const void* __restrict__ W1l, const void* __restrict__ W1r,
                                                const void* __restrict__ W2l, const void* __restrict__ W2r,
                                                const void* __restrict__ Wd,
                                                const void* __restrict__ b1, const void* __restrict__ b2,
                                                const void* __restrict__ bd,
                                                int* __restrict__ cntm, ushort_t* __restrict__ xb,
                                                ushort_t* __restrict__ wt, ushort_t* __restrict__ w2lt,
                                                ushort_t* __restrict__ w2rt, ushort_t* __restrict__ wdt,
                                                float* __restrict__ b1f, float* __restrict__ b2f,
                                                float* __restrict__ bdf) {
    __shared__ int flag;
    int b = blockIdx.x, t = threadIdx.x;
    if (b < NBK) {
        // --- coarse histogram ---
        int sh = detect_sh(ei, &flag);
        __shared__ int hist[NBUK];
        if (t < NBUK) hist[t] = 0;
        __syncthreads();
        for (int i = t; i < CHK; i += 256) {
            int e = b * CHK + i;
            if (e < NE) {
                int d = ei[(size_t)(NE + e) << sh];
                atomicAdd(&hist[d >> 8], 1);
            }
        }
        __syncthreads();
        if (t < NBUK) cntm[t * NBK + b] = hist[t];
    } else if (b < NBK + CVTB) {
        // --- x -> bf16 (x dead after this: non-temporal loads) ---
        int bf = detect_bf((const ushort_t*)x, &flag);
        int i = (b - NBK) * 256 + t;
        if (bf) {
            us4v v = __builtin_nontemporal_load(reinterpret_cast<const us4v*>(x) + i);
            *(reinterpret_cast<us4v*>(xb) + i) = v;
        } else {
            f4v v = __builtin_nontemporal_load(reinterpret_cast<const f4v*>(x) + i);
            us4v o;
            o.x = f2bf(v.x); o.y = f2bf(v.y); o.z = f2bf(v.z); o.w = f2bf(v.w);
            *(reinterpret_cast<us4v*>(xb) + i) = o;
        }
    } else {
        // --- weight/bias prep ---
        int bf = detect_bf((const ushort_t*)x, &flag);
        int idx = (b - NBK - CVTB) * 256 + t;
        if (idx < 65536) {
            int c = idx >> 8, k = idx & 255;
            float v = (k < 128) ? rdf(W1l, k * 256 + c, bf) : rdf(W1r, (k - 128) * 256 + c, bf);
            wt[c * 256 + k] = f2bf(v);
        } else if (idx < 81920) {
            int t2 = idx - 65536;
            int c = t2 >> 8, k = t2 & 255;
            w2lt[c * 256 + k] = f2bf(rdf(W2l, k * 64 + c, bf));
        } else if (idx < 98304) {
            int t2 = idx - 81920;
            int c = t2 >> 8, k = t2 & 255;
            w2rt[c * 256 + k] = f2bf(rdf(W2r, k * 64 + c, bf));
        } else if (idx < 106496) {
            int t2 = idx - 98304;
            int c = t2 >> 6, k = t2 & 63;
            wdt[c * 64 + k] = f2bf(rdf(Wd, k * 128 + c, bf));
        } else if (idx < 106752) {
            b1f[idx - 106496] = rdf(b1, idx - 106496, bf);
        } else if (idx < 106816) {
            b2f[idx - 106752] = rdf(b2, idx - 106752, bf);
        } else if (idx < 106944) {
            bdf[idx - 106816] = rdf(bd, idx - 106816, bf);
        }
    }
}

// ---------------- scan helper ----------------
__device__ inline int block_scan256(int v, int* ws, int* btot) {
    int lane = threadIdx.x & 63, wv = threadIdx.x >> 6;
    int incl = v;
#pragma unroll
    for (int d = 1; d < 64; d <<= 1) {
        int n = __shfl_up(incl, d);
        if (lane >= d) incl += n;
    }
    if (lane == 63) ws[wv] = incl;
    __syncthreads();
    if (threadIdx.x == 0) {
        int r = 0;
#pragma unroll
        for (int k = 0; k < 4; ++k) { int t = ws[k]; ws[k] = r; r += t; }
        *btot = r;
    }
    __syncthreads();
    return ws[wv] + incl - v;
}

// ---------------- coarse scatter: cursors derived directly from cntm (scanMA removed) ----------------
// cursor for bucket t at chunk blk = sum(rowsum[t'<t]) + sum(cntm[t][b'<blk])
__global__ __launch_bounds__(256) void k_scatterC(const int* __restrict__ ei, const int* __restrict__ cntm,
                                                  uint32_t* __restrict__ pairs) {
    __shared__ int cur[NBUK];
    __shared__ int ws[4]; __shared__ int btot;
    __shared__ int flag;
    int t = threadIdx.x, blk = blockIdx.x;
    int sh = detect_sh(ei, &flag);
    int rowsum = 0, part = 0;
    if (t < NBUK) {
        const int* row = cntm + t * NBK;
        for (int b2 = 0; b2 < NBK; ++b2) {
            int c = row[b2];
            rowsum += c;
            if (b2 < blk) part += c;
        }
    }
    int bpre = block_scan256(rowsum, ws, &btot);   // exclusive bucket prefix
    if (t < NBUK) cur[t] = bpre + part;
    __syncthreads();
    for (int i = t; i < CHK; i += 256) {
        int e = blk * CHK + i;
        if (e < NE) {
            int s = ei[(size_t)e << sh];
            int d = ei[(size_t)(NE + e) << sh];
            int pos = atomicAdd(&cur[d >> 8], 1);
            pairs[pos] = (uint32_t)s | ((uint32_t)(d & 255) << 16);
        }
    }
}

// ---------------- fused D1+scan+D2 (bucket bounds derived from cntm) ----------------
__global__ __launch_bounds__(256) void k_d12(const uint32_t* __restrict__ pairs, const int* __restrict__ cntm,
                                             int* __restrict__ rowptr, ushort_t* __restrict__ srclist) {
    __shared__ int hist[256];
    __shared__ int cur[256];
    __shared__ int bpreA[NBUK + 1];
    __shared__ int ws[4]; __shared__ int btot;
    int t = threadIdx.x, b = blockIdx.x;
    int rowsum = 0;
    if (t < NBUK) {
        const int* row = cntm + t * NBK;
        for (int b2 = 0; b2 < NBK; ++b2) rowsum += row[b2];
    }
    int bpre = block_scan256(rowsum, ws, &btot);
    if (t < NBUK) bpreA[t] = bpre;
    if (t == NBUK - 1) bpreA[NBUK] = bpre + rowsum;
    hist[t] = 0;
    __syncthreads();
    int beg = bpreA[b];
    int end = bpreA[b + 1];
    // pass 1: per-node degree histogram
    for (int i = beg + t; i < end; i += 256) {
        uint32_t p = pairs[i];
        atomicAdd(&hist[p >> 16], 1);
    }
    __syncthreads();
    int v = hist[t];
    int excl = block_scan256(v, ws, &btot);
    int node = b * 256 + t;
    int rp = beg + excl;
    if (node < NN) rowptr[node] = rp;
    cur[t] = rp;
    if (b == 0 && t == 0) rowptr[NN] = NE;
    __syncthreads();
    // pass 2: fine scatter
    for (int i = beg + t; i < end; i += 256) {
        uint32_t p = pairs[i];
        int pos = atomicAdd(&cur[p >> 16], 1);
        srclist[pos] = (ushort_t)(p & 0xffff);
    }
}

// ---------------- agg1: meanx (32 edges/iter per half-wave, 16 loads in flight) ----------------
__global__ __launch_bounds__(256) void k_agg128(const ushort_t* __restrict__ xb, const int* __restrict__ rowptr,
                                                const ushort_t* __restrict__ srclist, ushort_t* __restrict__ out) {
    int node = (blockIdx.x * 256 + threadIdx.x) >> 6;
    int lane = threadIdx.x & 63;
    if (node >= NN) return;
    int half = lane >> 5, l32 = lane & 31;   // lane covers bf16 cols l32*4 .. l32*4+3
    int beg = rowptr[node], end = rowptr[node + 1];
    float a0 = 0.f, a1 = 0.f, a2 = 0.f, a3 = 0.f;
    int j = beg + half;
    for (; j + 30 < end; j += 32) {
        ushort4 p[16];
#pragma unroll
        for (int u = 0; u < 16; ++u) {
            int s = srclist[j + 2 * u];
            p[u] = *reinterpret_cast<const ushort4*>(xb + (size_t)s * 128 + l32 * 4);
        }
#pragma unroll
        for (int u = 0; u < 16; ++u) {
            a0 += bf2f(p[u].x); a1 += bf2f(p[u].y); a2 += bf2f(p[u].z); a3 += bf2f(p[u].w);
        }
    }
    for (; j + 14 < end; j += 16) {
        ushort4 p[8];
#pragma unroll
        for (int u = 0; u < 8; ++u) {
            int s = srclist[j + 2 * u];
            p[u] = *reinterpret_cast<const ushort4*>(xb + (size_t)s * 128 + l32 * 4);
        }
#pragma unroll
        for (int u = 0; u < 8; ++u) {
            a0 += bf2f(p[u].x); a1 += bf2f(p[u].y); a2 += bf2f(p[u].z); a3 += bf2f(p[u].w);
        }
    }
    for (; j + 6 < end; j += 8) {
        ushort4 p[4];
#pragma unroll
        for (int u = 0; u < 4; ++u) {
            int s = srclist[j + 2 * u];
            p[u] = *reinterpret_cast<const ushort4*>(xb + (size_t)s * 128 + l32 * 4);
        }
#pragma unroll
        for (int u = 0; u < 4; ++u) {
            a0 += bf2f(p[u].x); a1 += bf2f(p[u].y); a2 += bf2f(p[u].z); a3 += bf2f(p[u].w);
        }
    }
    for (; j < end; j += 2) {
        int s = srclist[j];
        ushort4 p = *reinterpret_cast<const ushort4*>(xb + (size_t)s * 128 + l32 * 4);
        a0 += bf2f(p.x); a1 += bf2f(p.y); a2 += bf2f(p.z); a3 += bf2f(p.w);
    }
    a0 += __shfl_xor(a0, 32);
    a1 += __shfl_xor(a1, 32);
    a2 += __shfl_xor(a2, 32);
    a3 += __shfl_xor(a3, 32);
    if (half == 0) {
        float inv = 1.0f / (float)max(end - beg, 1);
        ushort4 o;
        o.x = f2bf(a0 * inv); o.y = f2bf(a1 * inv); o.z = f2bf(a2 * inv); o.w = f2bf(a3 * inv);
        *reinterpret_cast<ushort4*>(out + (size_t)node * 128 + l32 * 4) = o;
    }
}

// ---------------- fused GEMM1+GEMM2: h never touches global ----------------
__global__ __launch_bounds__(256, 2) void k_gemm12(const ushort_t* __restrict__ meanx, const ushort_t* __restrict__ xb,
                                                   const ushort_t* __restrict__ wt, const float* __restrict__ b1f,
                                                   const ushort_t* __restrict__ w2lt, const ushort_t* __restrict__ w2rt,
                                                   const float* __restrict__ b2f,
                                                   ushort_t* __restrict__ y, float* __restrict__ r) {
    __shared__ alignas(16) ushort_t ht[16 * 256];   // 8 KB, byte ^= (row&7)<<4 swizzle
    int wv = threadIdx.x >> 6, lane = threadIdx.x & 63;
    int m = lane & 15, q = lane >> 4;
    bf16x8 B1[8][4];
#pragma unroll
    for (int ks = 0; ks < 8; ++ks) {
        int kb = ks * 32 + q * 8;
#pragma unroll
        for (int ct = 0; ct < 4; ++ct)
            B1[ks][ct] = *reinterpret_cast<const bf16x8*>(wt + (size_t)(wv * 64 + ct * 16 + m) * 256 + kb);
    }
    int op = wv >> 1;
    int cb = (wv & 1) * 32;
    const ushort_t* wtx = op ? w2rt : w2lt;
    bf16x8 B2[8][2];
#pragma unroll
    for (int ks = 0; ks < 8; ++ks) {
        int kb = ks * 32 + q * 8;
#pragma unroll
        for (int ct = 0; ct < 2; ++ct)
            B2[ks][ct] = *reinterpret_cast<const bf16x8*>(wtx + (size_t)(cb + ct * 16 + m) * 256 + kb);
    }
    float bias2[2];
#pragma unroll
    for (int ct = 0; ct < 2; ++ct) bias2[ct] = b2f[cb + ct * 16 + m];

    const int ntiles = NN / 16;
    for (int t = blockIdx.x; t < ntiles; t += gridDim.x) {
        int r0 = t * 16;
        int row = r0 + m;
        // ---- phase 1: 16x256 h tile ----
        f32x4 acc[4];
#pragma unroll
        for (int ct = 0; ct < 4; ++ct) acc[ct] = (f32x4){0.f, 0.f, 0.f, 0.f};
#pragma unroll
        for (int ks = 0; ks < 8; ++ks) {
            int kb = ks * 32 + q * 8;
            const ushort_t* ap = (ks < 4) ? (meanx + (size_t)row * 128 + kb)
                                          : (xb + (size_t)row * 128 + (kb - 128));
            bf16x8 a = *reinterpret_cast<const bf16x8*>(ap);
#pragma unroll
            for (int ct = 0; ct < 4; ++ct)
                acc[ct] = __builtin_amdgcn_mfma_f32_16x16x32_bf16(a, B1[ks][ct], acc[ct], 0, 0, 0);
        }
#pragma unroll
        for (int ct = 0; ct < 4; ++ct) {
            int c = wv * 64 + ct * 16 + m;
            float bias = b1f[c];
#pragma unroll
            for (int i = 0; i < 4; ++i) {
                int lr = q * 4 + i;
                int off = (lr * 512 + c * 2) ^ ((lr & 7) << 4);
                *reinterpret_cast<ushort_t*>(reinterpret_cast<char*>(ht) + off) =
                    f2bf(fmaxf(acc[ct][i] + bias, 0.f));
            }
        }
        __syncthreads();
        // ---- phase 2: y / r from LDS h tile ----
        f32x4 acc2[2];
        acc2[0] = (f32x4){0.f, 0.f, 0.f, 0.f}; acc2[1] = acc2[0];
#pragma unroll
        for (int ks = 0; ks < 8; ++ks) {
            int boff = (m * 512 + ks * 64 + q * 16) ^ ((m & 7) << 4);
            bf16x8 a = *reinterpret_cast<const bf16x8*>(reinterpret_cast<const char*>(ht) + boff);
#pragma unroll
            for (int ct = 0; ct < 2; ++ct)
                acc2[ct] = __builtin_amdgcn_mfma_f32_16x16x32_bf16(a, B2[ks][ct], acc2[ct], 0, 0, 0);
        }
#pragma unroll
        for (int ct = 0; ct < 2; ++ct) {
            int c = cb + ct * 16 + m;
#pragma unroll
            for (int i = 0; i < 4; ++i) {
                int rr = r0 + q * 4 + i;
                if (op == 0) y[(size_t)rr * 64 + c] = f2bf(acc2[ct][i]);
                else         r[(size_t)rr * 64 + c] = acc2[ct][i] + bias2[ct];
            }
        }
        __syncthreads();
    }
}

// ---------------- fused agg2 + GEMM3 (4 edges per VMEM inst; nt stores for outputs) ----------------
__global__ __launch_bounds__(256) void k_agg2g3(const ushort_t* __restrict__ y, const int* __restrict__ rowptr,
                                                const ushort_t* __restrict__ srclist,
                                                float* zr,
                                                const ushort_t* __restrict__ wdt, const float* __restrict__ bdf,
                                                float* __restrict__ xhat) {
    __shared__ alignas(16) ushort_t zt[16][72];
    int b = blockIdx.x;
    int wv = threadIdx.x >> 6, lane = threadIdx.x & 63;
    int m = lane & 15, q = lane >> 4;
    bf16x8 B[2][2];
#pragma unroll
    for (int ks = 0; ks < 2; ++ks) {
        int kb = ks * 32 + q * 8;
#pragma unroll
        for (int ct = 0; ct < 2; ++ct)
            B[ks][ct] = *reinterpret_cast<const bf16x8*>(wdt + (size_t)(wv * 32 + ct * 16 + m) * 64 + kb);
    }
    float bias0 = bdf[wv * 32 + m], bias1 = bdf[wv * 32 + 16 + m];

    int quarter = lane >> 4, l16 = lane & 15;   // lane covers bf16 cols l16*4 .. +3
#pragma unroll
    for (int s = 0; s < 4; ++s) {
        int node = b * 16 + wv * 4 + s;
        int beg = rowptr[node], end = rowptr[node + 1];
        float a0 = 0.f, a1 = 0.f, a2 = 0.f, a3 = 0.f;
        int j = beg + quarter;
        for (; j + 12 < end; j += 16) {
            ushort4 p[4];
#pragma unroll
            for (int u = 0; u < 4; ++u) {
                int sx = srclist[j + 4 * u];
                p[u] = *reinterpret_cast<const ushort4*>(y + (size_t)sx * 64 + l16 * 4);
            }
#pragma unroll
            for (int u = 0; u < 4; ++u) {
                a0 += bf2f(p[u].x); a1 += bf2f(p[u].y); a2 += bf2f(p[u].z); a3 += bf2f(p[u].w);
            }
        }
        for (; j < end; j += 4) {
            int sx = srclist[j];
            ushort4 p = *reinterpret_cast<const ushort4*>(y + (size_t)sx * 64 + l16 * 4);
            a0 += bf2f(p.x); a1 += bf2f(p.y); a2 += bf2f(p.z); a3 += bf2f(p.w);
        }
        a0 += __shfl_xor(a0, 16); a0 += __shfl_xor(a0, 32);
        a1 += __shfl_xor(a1, 16); a1 += __shfl_xor(a1, 32);
        a2 += __shfl_xor(a2, 16); a2 += __shfl_xor(a2, 32);
        a3 += __shfl_xor(a3, 16); a3 += __shfl_xor(a3, 32);
        if (quarter == 0) {
            float inv = 1.0f / (float)max(end - beg, 1);
            float4 rv = *reinterpret_cast<const float4*>(zr + (size_t)node * 64 + l16 * 4);
            f4v zo;
            zo.x = a0 * inv + rv.x;
            zo.y = a1 * inv + rv.y;
            zo.z = a2 * inv + rv.z;
            zo.w = a3 * inv + rv.w;
            __builtin_nontemporal_store(zo, reinterpret_cast<f4v*>(zr + (size_t)node * 64 + l16 * 4));
            uint2 o;
            o.x = (uint32_t)f2bf(zo.x) | ((uint32_t)f2bf(zo.y) << 16);
            o.y = (uint32_t)f2bf(zo.z) | ((uint32_t)f2bf(zo.w) << 16);
            *reinterpret_cast<uint2*>(&zt[wv * 4 + s][l16 * 4]) = o;
        }
    }
    __syncthreads();
    f32x4 acc[2];
    acc[0] = (f32x4){0.f, 0.f, 0.f, 0.f}; acc[1] = acc[0];
#pragma unroll
    for (int ks = 0; ks < 2; ++ks) {
        bf16x8 a = *reinterpret_cast<const bf16x8*>(&zt[m][ks * 32 + q * 8]);
#pragma unroll
        for (int ct = 0; ct < 2; ++ct)
            acc[ct] = __builtin_amdgcn_mfma_f32_16x16x32_bf16(a, B[ks][ct], acc[ct], 0, 0, 0);
    }
#pragma unroll
    for (int ct = 0; ct < 2; ++ct) {
        int c = wv * 32 + ct * 16 + m;
        float bb = ct ? bias1 : bias0;
#pragma unroll
        for (int i = 0; i < 4; ++i) {
            int rr = b * 16 + q * 4 + i;
            __builtin_nontemporal_store(acc[ct][i] + bb, &xhat[(size_t)rr * 128 + c]);
        }
    }
}

extern "C" void kernel_launch(void* const* d_in, const int* in_sizes, int n_in,
                              void* d_out, int out_size, void* d_ws, size_t ws_size,
                              hipStream_t stream) {
    const void *px = nullptr, *pei = nullptr, *pW1l = nullptr, *pW1r = nullptr,
               *pW2l = nullptr, *pW2r = nullptr, *pWd = nullptr,
               *pb1 = nullptr, *pb2 = nullptr, *pbd = nullptr;
    for (int i = 0; i < n_in; ++i) {
        const void* p = d_in[i];
        switch (in_sizes[i]) {
            case 6400000: px  = p; break;
            case 1600000: pei = p; break;
            case 32768:   if (!pW1l) pW1l = p; else pW1r = p; break;
            case 16384:   if (!pW2l) pW2l = p; else pW2r = p; break;
            case 8192:    pWd = p; break;
            case 256:     pb1 = p; break;
            case 128:     pbd = p; break;
            case 64:      pb2 = p; break;
            default: break;
        }
    }
    if (!px || !pei || !pW1l || !pW1r || !pW2l || !pW2r || !pWd || !pb1 || !pb2 || !pbd) {
        px = d_in[0]; pei = d_in[1]; pW1l = d_in[2]; pb1 = d_in[3]; pW1r = d_in[4];
        pW2l = d_in[5]; pb2 = d_in[6]; pW2r = d_in[7]; pWd = d_in[8]; pbd = d_in[9];
    }
    const int* ei = (const int*)pei;

    char* base = (char*)d_ws;
    size_t off = 0;
    auto alloc = [&](size_t bytes) -> void* {
        void* r = base + off;
        off = (off + bytes + 255) & ~(size_t)255;
        return r;
    };
    int* rowptr   = (int*)alloc((size_t)(NN + 1) * 4);
    int* cntm     = (int*)alloc((size_t)MTOT * 4);
    uint32_t* pairs = (uint32_t*)alloc((size_t)NE * 4);
    ushort_t* srclist = (ushort_t*)alloc((size_t)NE * 2);
    ushort_t* wt   = (ushort_t*)alloc((size_t)65536 * 2);
    ushort_t* w2lt = (ushort_t*)alloc((size_t)16384 * 2);
    ushort_t* w2rt = (ushort_t*)alloc((size_t)16384 * 2);
    ushort_t* wdt  = (ushort_t*)alloc((size_t)8192 * 2);
    float* b1f    = (float*)alloc(256 * 4);
    float* b2f    = (float*)alloc(64 * 4);
    float* bdf    = (float*)alloc(128 * 4);
    ushort_t* xb  = (ushort_t*)alloc((size_t)NN * 128 * 2);
    ushort_t* y   = (ushort_t*)alloc((size_t)NN * 64 * 2);   // own region: xb live through gemm12

    float* out_z    = (float*)d_out;
    float* out_xhat = out_z + (size_t)NN * 64;

    ushort_t* meanx = (ushort_t*)out_xhat;   // dead before xhat written
    float*    rbuf  = out_z;                 // r written here, z computed IN PLACE

    k_stage1<<<NBK + CVTB + PREPB, 256, 0, stream>>>(ei, px, pW1l, pW1r, pW2l, pW2r, pWd, pb1, pb2, pbd,
                                                     cntm, xb, wt, w2lt, w2rt, wdt, b1f, b2f, bdf);

    k_scatterC<<<NBK, 256, 0, stream>>>(ei, cntm, pairs);
    k_d12<<<NBUK, 256, 0, stream>>>(pairs, cntm, rowptr, srclist);

    int ab = (NN + 3) / 4;
    k_agg128<<<ab, 256, 0, stream>>>(xb, rowptr, srclist, meanx);

    k_gemm12<<<512, 256, 0, stream>>>(meanx, xb, wt, b1f, w2lt, w2rt, b2f, y, rbuf);
    k_agg2g3<<<NN / 16, 256, 0, stream>>>(y, rowptr, srclist, rbuf, wdt, bdf, out_xhat);
}

// Round 11
// 219.954 us; speedup vs baseline: 1.0273x; 1.0273x over previous
//
#include <hip/hip_runtime.h>
#include <stdint.h>

#define NN 50000
#define NE 800000
#define NB 196     // scan blocks over nodes
#define NBK 196    // edge chunks
#define NBUK 196   // dst buckets of 256 nodes
#define CHK 4096   // edges per chunk
#define MTOT (NBUK * NBK)   // 38416
#define MSB 151    // scan blocks over MTOT
#define CVTB 6250  // cvt blocks: NN*128/4/256
#define PREPB 418  // prep blocks
// IN=128, HID=256, LAT=64

typedef __bf16 bf16x8 __attribute__((ext_vector_type(8)));
typedef float f32x4 __attribute__((ext_vector_type(4)));
typedef unsigned short ushort_t;
typedef unsigned short us4v __attribute__((ext_vector_type(4)));   // native vec for nt builtins
typedef float f4v __attribute__((ext_vector_type(4)));

__device__ inline float bf2f(uint16_t u) {
    union { uint32_t i; float f; } v; v.i = ((uint32_t)u) << 16; return v.f;
}
__device__ inline uint16_t f2bf(float f) {
    uint32_t u = __float_as_uint(f);
    u += 0x7fffu + ((u >> 16) & 1u);
    return (uint16_t)(u >> 16);
}
__device__ inline float rdf(const void* p, int i, int bf) {
    return bf ? bf2f(((const ushort_t*)p)[i]) : ((const float*)p)[i];
}

// ---------------- block-local mode detection ----------------
__device__ inline int blk_or(int v, int* flag) {
    if (threadIdx.x == 0) *flag = 0;
    __syncthreads();
    if (v) atomicOr(flag, 1);
    __syncthreads();
    return *flag;
}
// 1 => ei is int64 (index low words via <<1), 0 => int32
__device__ inline int detect_sh(const int* __restrict__ ei, int* flag) {
    int t = threadIdx.x;
    int v = ei[2 * t + 1] | ei[2 * (t + 256) + 1] | ei[2 * (t + 512) + 1] | ei[2 * (t + 768) + 1];
    return blk_or(v, flag) ? 0 : 1;
}
// 1 => x is bf16, 0 => f32
__device__ inline int detect_bf(const ushort_t* __restrict__ xw, int* flag) {
    int t = threadIdx.x;
    int bad = 0;
#pragma unroll
    for (int r = 0; r < 2; ++r) {
        uint16_t w = xw[t + 256 * r];
        int e = (w >> 7) & 0xFF;
        if (!(w == 0 || (e >= 96 && e <= 144))) bad = 1;
    }
    return blk_or(bad, flag) ? 0 : 1;
}

// ---------------- stage1: histA ∥ cvt ∥ prep3 in one grid ----------------
__global__ __launch_bounds__(256) void k_stage1(const int* __restrict__ ei, const void* __restrict__ x,
                                                const void* __restrict__ W1l, const void* __restrict__ W1r,
                                                const void* __restrict__ W2l, const void* __restrict__ W2r,
                                                const void* __restrict__ Wd,
                                                const void* __restrict__ b1, const void* __restrict__ b2,
                                                const void* __restrict__ bd,
                                                int* __restrict__ cntm, ushort_t* __restrict__ xb,
                                                ushort_t* __restrict__ wt, ushort_t* __restrict__ w2lt,
                                                ushort_t* __restrict__ w2rt, ushort_t* __restrict__ wdt,
                                                float* __restrict__ b1f, float* __restrict__ b2f,
                                                float* __restrict__ bdf) {
    __shared__ int flag;
    int b = blockIdx.x, t = threadIdx.x;
    if (b < NBK) {
        // --- coarse histogram ---
        int sh = detect_sh(ei, &flag);
        __shared__ int hist[NBUK];
        if (t < NBUK) hist[t] = 0;
        __syncthreads();
        for (int i = t; i < CHK; i += 256) {
            int e = b * CHK + i;
            if (e < NE) {
                int d = ei[(size_t)(NE + e) << sh];
                atomicAdd(&hist[d >> 8], 1);
            }
        }
        __syncthreads();
        if (t < NBUK) cntm[t * NBK + b] = hist[t];
    } else if (b < NBK + CVTB) {
        // --- x -> bf16 (x dead after this: non-temporal loads) ---
        int bf = detect_bf((const ushort_t*)x, &flag);
        int i = (b - NBK) * 256 + t;
        if (bf) {
            us4v v = __builtin_nontemporal_load(reinterpret_cast<const us4v*>(x) + i);
            *(reinterpret_cast<us4v*>(xb) + i) = v;
        } else {
            f4v v = __builtin_nontemporal_load(reinterpret_cast<const f4v*>(x) + i);
            us4v o;
            o.x = f2bf(v.x); o.y = f2bf(v.y); o.z = f2bf(v.z); o.w = f2bf(v.w);
            *(reinterpret_cast<us4v*>(xb) + i) = o;
        }
    } else {
        // --- weight/bias prep ---
        int bf = detect_bf((const ushort_t*)x, &flag);
        int idx = (b - NBK - CVTB) * 256 + t;
        if (idx < 65536) {
            int c = idx >> 8, k = idx & 255;
            float v = (k < 128) ? rdf(W1l, k * 256 + c, bf) : rdf(W1r, (k - 128) * 256 + c, bf);
            wt[c * 256 + k] = f2bf(v);
        } else if (idx < 81920) {
            int t2 = idx - 65536;
            int c = t2 >> 8, k = t2 & 255;
            w2lt[c * 256 + k] = f2bf(rdf(W2l, k * 64 + c, bf));
        } else if (idx < 98304) {
            int t2 = idx - 81920;
            int c = t2 >> 8, k = t2 & 255;
            w2rt[c * 256 + k] = f2bf(rdf(W2r, k * 64 + c, bf));
        } else if (idx < 106496) {
            int t2 = idx - 98304;
            int c = t2 >> 6, k = t2 & 63;
            wdt[c * 64 + k] = f2bf(rdf(Wd, k * 128 + c, bf));
        } else if (idx < 106752) {
            b1f[idx - 106496] = rdf(b1, idx - 106496, bf);
        } else if (idx < 106816) {
            b2f[idx - 106752] = rdf(b2, idx - 106752, bf);
        } else if (idx < 106944) {
            bdf[idx - 106816] = rdf(bd, idx - 106816, bf);
        }
    }
}

// ---------------- scan helpers ----------------
__device__ inline int block_scan256(int v, int* ws, int* btot) {
    int lane = threadIdx.x & 63, wv = threadIdx.x >> 6;
    int incl = v;
#pragma unroll
    for (int d = 1; d < 64; d <<= 1) {
        int n = __shfl_up(incl, d);
        if (lane >= d) incl += n;
    }
    if (lane == 63) ws[wv] = incl;
    __syncthreads();
    if (threadIdx.x == 0) {
        int r = 0;
#pragma unroll
        for (int k = 0; k < 4; ++k) { int t = ws[k]; ws[k] = r; r += t; }
        *btot = r;
    }
    __syncthreads();
    return ws[wv] + incl - v;
}

// scanMA: offm = within-scan-block exclusive scan of cntm; bsM = per-scan-block totals
__global__ __launch_bounds__(256) void k_scanMA(const int* __restrict__ cntm, int* __restrict__ offm,
                                                int* __restrict__ bsM) {
    __shared__ int ws[4]; __shared__ int btot;
    int i = blockIdx.x * 256 + threadIdx.x;
    int v = (i < MTOT) ? cntm[i] : 0;
    int excl = block_scan256(v, ws, &btot);
    if (i < MTOT) offm[i] = excl;
    if (threadIdx.x == 0) bsM[blockIdx.x] = btot;
}

// local exclusive prefix of bsM into shared bsPre[256] (valid for idx < 256)
__device__ inline void bsm_prefix(const int* __restrict__ bsM, int* bsPre, int* ws, int* btot) {
    int t = threadIdx.x;
    int v = (t < MSB) ? bsM[t] : 0;
    int excl = block_scan256(v, ws, &btot[0]);
    bsPre[t] = excl;
    __syncthreads();
}

// ---------------- phase C: coarse scatter (LDS cursors, local bsM prefix) ----------------
__global__ __launch_bounds__(256) void k_scatterC(const int* __restrict__ ei,
                                                  const int* __restrict__ offm, const int* __restrict__ bsM,
                                                  uint32_t* __restrict__ pairs) {
    __shared__ int cur[NBUK];
    __shared__ int bsPre[256];
    __shared__ int ws[4]; __shared__ int btot;
    __shared__ int flag;
    int t = threadIdx.x, blk = blockIdx.x;
    int sh = detect_sh(ei, &flag);
    bsm_prefix(bsM, bsPre, ws, &btot);
    if (t < NBUK) {
        int g = t * NBK + blk;
        cur[t] = offm[g] + bsPre[g >> 8];
    }
    __syncthreads();
    for (int i = t; i < CHK; i += 256) {
        int e = blk * CHK + i;
        if (e < NE) {
            int s = ei[(size_t)e << sh];
            int d = ei[(size_t)(NE + e) << sh];
            int pos = atomicAdd(&cur[d >> 8], 1);
            pairs[pos] = (uint32_t)s | ((uint32_t)(d & 255) << 16);
        }
    }
}

// ---------------- fused D1+scan+D2 ----------------
__global__ __launch_bounds__(256) void k_d12(const uint32_t* __restrict__ pairs, const int* __restrict__ offm,
                                             const int* __restrict__ bsM,
                                             int* __restrict__ rowptr, ushort_t* __restrict__ srclist) {
    __shared__ int hist[256];
    __shared__ int cur[256];
    __shared__ int bsPre[256];
    __shared__ int ws[4]; __shared__ int btot;
    int t = threadIdx.x, b = blockIdx.x;
    bsm_prefix(bsM, bsPre, ws, &btot);
    __shared__ int sbeg, send;
    if (t == 0) {
        int g0 = b * NBK;
        sbeg = offm[g0] + bsPre[g0 >> 8];
        if (b + 1 < NBUK) {
            int g1 = (b + 1) * NBK;
            send = offm[g1] + bsPre[g1 >> 8];
        } else {
            send = NE;
        }
    }
    hist[t] = 0;
    __syncthreads();
    int beg = sbeg, end = send;
    for (int i = beg + t; i < end; i += 256) {
        uint32_t p = pairs[i];
        atomicAdd(&hist[p >> 16], 1);
    }
    __syncthreads();
    int v = hist[t];
    int excl = block_scan256(v, ws, &btot);
    int node = b * 256 + t;
    int rp = beg + excl;
    if (node < NN) rowptr[node] = rp;
    cur[t] = rp;
    if (b == 0 && t == 0) rowptr[NN] = NE;
    __syncthreads();
    for (int i = beg + t; i < end; i += 256) {
        uint32_t p = pairs[i];
        int pos = atomicAdd(&cur[p >> 16], 1);
        srclist[pos] = (ushort_t)(p & 0xffff);
    }
}

// ---------------- agg1: meanx (2 edges per VMEM inst, 16 edges in flight) ----------------
__global__ __launch_bounds__(256) void k_agg128(const ushort_t* __restrict__ xb, const int* __restrict__ rowptr,
                                                const ushort_t* __restrict__ srclist, ushort_t* __restrict__ out) {
    int node = (blockIdx.x * 256 + threadIdx.x) >> 6;
    int lane = threadIdx.x & 63;
    if (node >= NN) return;
    int half = lane >> 5, l32 = lane & 31;   // lane covers bf16 cols l32*4 .. l32*4+3
    int beg = rowptr[node], end = rowptr[node + 1];
    float a0 = 0.f, a1 = 0.f, a2 = 0.f, a3 = 0.f;
    int j = beg + half;
    for (; j + 14 < end; j += 16) {
        ushort4 p[8];
#pragma unroll
        for (int u = 0; u < 8; ++u) {
            int s = srclist[j + 2 * u];
            p[u] = *reinterpret_cast<const ushort4*>(xb + (size_t)s * 128 + l32 * 4);
        }
#pragma unroll
        for (int u = 0; u < 8; ++u) {
            a0 += bf2f(p[u].x); a1 += bf2f(p[u].y); a2 += bf2f(p[u].z); a3 += bf2f(p[u].w);
        }
    }
    for (; j + 6 < end; j += 8) {
        ushort4 p[4];
#pragma unroll
        for (int u = 0; u < 4; ++u) {
            int s = srclist[j + 2 * u];
            p[u] = *reinterpret_cast<const ushort4*>(xb + (size_t)s * 128 + l32 * 4);
        }
#pragma unroll
        for (int u = 0; u < 4; ++u) {
            a0 += bf2f(p[u].x); a1 += bf2f(p[u].y); a2 += bf2f(p[u].z); a3 += bf2f(p[u].w);
        }
    }
    for (; j < end; j += 2) {
        int s = srclist[j];
        ushort4 p = *reinterpret_cast<const ushort4*>(xb + (size_t)s * 128 + l32 * 4);
        a0 += bf2f(p.x); a1 += bf2f(p.y); a2 += bf2f(p.z); a3 += bf2f(p.w);
    }
    a0 += __shfl_xor(a0, 32);
    a1 += __shfl_xor(a1, 32);
    a2 += __shfl_xor(a2, 32);
    a3 += __shfl_xor(a3, 32);
    if (half == 0) {
        float inv = 1.0f / (float)max(end - beg, 1);
        ushort4 o;
        o.x = f2bf(a0 * inv); o.y = f2bf(a1 * inv); o.z = f2bf(a2 * inv); o.w = f2bf(a3 * inv);
        *reinterpret_cast<ushort4*>(out + (size_t)node * 128 + l32 * 4) = o;
    }
}

// ---------------- fused GEMM1+GEMM2: h never touches global ----------------
__global__ __launch_bounds__(256, 2) void k_gemm12(const ushort_t* __restrict__ meanx, const ushort_t* __restrict__ xb,
                                                   const ushort_t* __restrict__ wt, const float* __restrict__ b1f,
                                                   const ushort_t* __restrict__ w2lt, const ushort_t* __restrict__ w2rt,
                                                   const float* __restrict__ b2f,
                                                   ushort_t* __restrict__ y, float* __restrict__ r) {
    __shared__ alignas(16) ushort_t ht[16 * 256];   // 8 KB, byte ^= (row&7)<<4 swizzle
    int wv = threadIdx.x >> 6, lane = threadIdx.x & 63;
    int m = lane & 15, q = lane >> 4;
    bf16x8 B1[8][4];
#pragma unroll
    for (int ks = 0; ks < 8; ++ks) {
        int kb = ks * 32 + q * 8;
#pragma unroll
        for (int ct = 0; ct < 4; ++ct)
            B1[ks][ct] = *reinterpret_cast<const bf16x8*>(wt + (size_t)(wv * 64 + ct * 16 + m) * 256 + kb);
    }
    int op = wv >> 1;
    int cb = (wv & 1) * 32;
    const ushort_t* wtx = op ? w2rt : w2lt;
    bf16x8 B2[8][2];
#pragma unroll
    for (int ks = 0; ks < 8; ++ks) {
        int kb = ks * 32 + q * 8;
#pragma unroll
        for (int ct = 0; ct < 2; ++ct)
            B2[ks][ct] = *reinterpret_cast<const bf16x8*>(wtx + (size_t)(cb + ct * 16 + m) * 256 + kb);
    }
    float bias2[2];
#pragma unroll
    for (int ct = 0; ct < 2; ++ct) bias2[ct] = b2f[cb + ct * 16 + m];

    const int ntiles = NN / 16;
    for (int t = blockIdx.x; t < ntiles; t += gridDim.x) {
        int r0 = t * 16;
        int row = r0 + m;
        // ---- phase 1: 16x256 h tile ----
        f32x4 acc[4];
#pragma unroll
        for (int ct = 0; ct < 4; ++ct) acc[ct] = (f32x4){0.f, 0.f, 0.f, 0.f};
#pragma unroll
        for (int ks = 0; ks < 8; ++ks) {
            int kb = ks * 32 + q * 8;
            const ushort_t* ap = (ks < 4) ? (meanx + (size_t)row * 128 + kb)
                                          : (xb + (size_t)row * 128 + (kb - 128));
            bf16x8 a = *reinterpret_cast<const bf16x8*>(ap);
#pragma unroll
            for (int ct = 0; ct < 4; ++ct)
                acc[ct] = __builtin_amdgcn_mfma_f32_16x16x32_bf16(a, B1[ks][ct], acc[ct], 0, 0, 0);
        }
#pragma unroll
        for (int ct = 0; ct < 4; ++ct) {
            int c = wv * 64 + ct * 16 + m;
            float bias = b1f[c];
#pragma unroll
            for (int i = 0; i < 4; ++i) {
                int lr = q * 4 + i;
                int off = (lr * 512 + c * 2) ^ ((lr & 7) << 4);
                *reinterpret_cast<ushort_t*>(reinterpret_cast<char*>(ht) + off) =
                    f2bf(fmaxf(acc[ct][i] + bias, 0.f));
            }
        }
        __syncthreads();
        // ---- phase 2: y / r from LDS h tile ----
        f32x4 acc2[2];
        acc2[0] = (f32x4){0.f, 0.f, 0.f, 0.f}; acc2[1] = acc2[0];
#pragma unroll
        for (int ks = 0; ks < 8; ++ks) {
            int boff = (m * 512 + ks * 64 + q * 16) ^ ((m & 7) << 4);
            bf16x8 a = *reinterpret_cast<const bf16x8*>(reinterpret_cast<const char*>(ht) + boff);
#pragma unroll
            for (int ct = 0; ct < 2; ++ct)
                acc2[ct] = __builtin_amdgcn_mfma_f32_16x16x32_bf16(a, B2[ks][ct], acc2[ct], 0, 0, 0);
        }
#pragma unroll
        for (int ct = 0; ct < 2; ++ct) {
            int c = cb + ct * 16 + m;
#pragma unroll
            for (int i = 0; i < 4; ++i) {
                int rr = r0 + q * 4 + i;
                if (op == 0) y[(size_t)rr * 64 + c] = f2bf(acc2[ct][i]);
                else         r[(size_t)rr * 64 + c] = acc2[ct][i] + bias2[ct];
            }
        }
        __syncthreads();
    }
}

// ---------------- fused agg2 + GEMM3 (4 edges per VMEM inst; nt stores for outputs) ----------------
__global__ __launch_bounds__(256) void k_agg2g3(const ushort_t* __restrict__ y, const int* __restrict__ rowptr,
                                                const ushort_t* __restrict__ srclist,
                                                float* zr,
                                                const ushort_t* __restrict__ wdt, const float* __restrict__ bdf,
                                                float* __restrict__ xhat) {
    __shared__ alignas(16) ushort_t zt[16][72];
    int b = blockIdx.x;
    int wv = threadIdx.x >> 6, lane = threadIdx.x & 63;
    int m = lane & 15, q = lane >> 4;
    bf16x8 B[2][2];
#pragma unroll
    for (int ks = 0; ks < 2; ++ks) {
        int kb = ks * 32 + q * 8;
#pragma unroll
        for (int ct = 0; ct < 2; ++ct)
            B[ks][ct] = *reinterpret_cast<const bf16x8*>(wdt + (size_t)(wv * 32 + ct * 16 + m) * 64 + kb);
    }
    float bias0 = bdf[wv * 32 + m], bias1 = bdf[wv * 32 + 16 + m];

    int quarter = lane >> 4, l16 = lane & 15;   // lane covers bf16 cols l16*4 .. +3
#pragma unroll
    for (int s = 0; s < 4; ++s) {
        int node = b * 16 + wv * 4 + s;
        int beg = rowptr[node], end = rowptr[node + 1];
        float a0 = 0.f, a1 = 0.f, a2 = 0.f, a3 = 0.f;
        int j = beg + quarter;
        for (; j + 12 < end; j += 16) {
            ushort4 p[4];
#pragma unroll
            for (int u = 0; u < 4; ++u) {
                int sx = srclist[j + 4 * u];
                p[u] = *reinterpret_cast<const ushort4*>(y + (size_t)sx * 64 + l16 * 4);
            }
#pragma unroll
            for (int u = 0; u < 4; ++u) {
                a0 += bf2f(p[u].x); a1 += bf2f(p[u].y); a2 += bf2f(p[u].z); a3 += bf2f(p[u].w);
            }
        }
        for (; j < end; j += 4) {
            int sx = srclist[j];
            ushort4 p = *reinterpret_cast<const ushort4*>(y + (size_t)sx * 64 + l16 * 4);
            a0 += bf2f(p.x); a1 += bf2f(p.y); a2 += bf2f(p.z); a3 += bf2f(p.w);
        }
        a0 += __shfl_xor(a0, 16); a0 += __shfl_xor(a0, 32);
        a1 += __shfl_xor(a1, 16); a1 += __shfl_xor(a1, 32);
        a2 += __shfl_xor(a2, 16); a2 += __shfl_xor(a2, 32);
        a3 += __shfl_xor(a3, 16); a3 += __shfl_xor(a3, 32);
        if (quarter == 0) {
            float inv = 1.0f / (float)max(end - beg, 1);
            float4 rv = *reinterpret_cast<const float4*>(zr + (size_t)node * 64 + l16 * 4);
            f4v zo;
            zo.x = a0 * inv + rv.x;
            zo.y = a1 * inv + rv.y;
            zo.z = a2 * inv + rv.z;
            zo.w = a3 * inv + rv.w;
            __builtin_nontemporal_store(zo, reinterpret_cast<f4v*>(zr + (size_t)node * 64 + l16 * 4));
            uint2 o;
            o.x = (uint32_t)f2bf(zo.x) | ((uint32_t)f2bf(zo.y) << 16);
            o.y = (uint32_t)f2bf(zo.z) | ((uint32_t)f2bf(zo.w) << 16);
            *reinterpret_cast<uint2*>(&zt[wv * 4 + s][l16 * 4]) = o;
        }
    }
    __syncthreads();
    f32x4 acc[2];
    acc[0] = (f32x4){0.f, 0.f, 0.f, 0.f}; acc[1] = acc[0];
#pragma unroll
    for (int ks = 0; ks < 2; ++ks) {
        bf16x8 a = *reinterpret_cast<const bf16x8*>(&zt[m][ks * 32 + q * 8]);
#pragma unroll
        for (int ct = 0; ct < 2; ++ct)
            acc[ct] = __builtin_amdgcn_mfma_f32_16x16x32_bf16(a, B[ks][ct], acc[ct], 0, 0, 0);
    }
#pragma unroll
    for (int ct = 0; ct < 2; ++ct) {
        int c = wv * 32 + ct * 16 + m;
        float bb = ct ? bias1 : bias0;
#pragma unroll
        for (int i = 0; i < 4; ++i) {
            int rr = b * 16 + q * 4 + i;
            __builtin_nontemporal_store(acc[ct][i] + bb, &xhat[(size_t)rr * 128 + c]);
        }
    }
}

extern "C" void kernel_launch(void* const* d_in, const int* in_sizes, int n_in,
                              void* d_out, int out_size, void* d_ws, size_t ws_size,
                              hipStream_t stream) {
    const void *px = nullptr, *pei = nullptr, *pW1l = nullptr, *pW1r = nullptr,
               *pW2l = nullptr, *pW2r = nullptr, *pWd = nullptr,
               *pb1 = nullptr, *pb2 = nullptr, *pbd = nullptr;
    for (int i = 0; i < n_in; ++i) {
        const void* p = d_in[i];
        switch (in_sizes[i]) {
            case 6400000: px  = p; break;
            case 1600000: pei = p; break;
            case 32768:   if (!pW1l) pW1l = p; else pW1r = p; break;
            case 16384:   if (!pW2l) pW2l = p; else pW2r = p; break;
            case 8192:    pWd = p; break;
            case 256:     pb1 = p; break;
            case 128:     pbd = p; break;
            case 64:      pb2 = p; break;
            default: break;
        }
    }
    if (!px || !pei || !pW1l || !pW1r || !pW2l || !pW2r || !pWd || !pb1 || !pb2 || !pbd) {
        px = d_in[0]; pei = d_in[1]; pW1l = d_in[2]; pb1 = d_in[3]; pW1r = d_in[4];
        pW2l = d_in[5]; pb2 = d_in[6]; pW2r = d_in[7]; pWd = d_in[8]; pbd = d_in[9];
    }
    const int* ei = (const int*)pei;

    char* base = (char*)d_ws;
    size_t off = 0;
    auto alloc = [&](size_t bytes) -> void* {
        void* r = base + off;
        off = (off + bytes + 255) & ~(size_t)255;
        return r;
    };
    int* rowptr   = (int*)alloc((size_t)(NN + 1) * 4);
    int* cntm     = (int*)alloc((size_t)MTOT * 4);
    int* offm     = (int*)alloc((size_t)MTOT * 4);
    int* bsM      = (int*)alloc(256 * 4);
    uint32_t* pairs = (uint32_t*)alloc((size_t)NE * 4);
    ushort_t* srclist = (ushort_t*)alloc((size_t)NE * 2);
    ushort_t* wt   = (ushort_t*)alloc((size_t)65536 * 2);
    ushort_t* w2lt = (ushort_t*)alloc((size_t)16384 * 2);
    ushort_t* w2rt = (ushort_t*)alloc((size_t)16384 * 2);
    ushort_t* wdt  = (ushort_t*)alloc((size_t)8192 * 2);
    float* b1f    = (float*)alloc(256 * 4);
    float* b2f    = (float*)alloc(64 * 4);
    float* bdf    = (float*)alloc(128 * 4);
    ushort_t* xb  = (ushort_t*)alloc((size_t)NN * 128 * 2);
    ushort_t* y   = (ushort_t*)alloc((size_t)NN * 64 * 2);   // own region: xb live through gemm12

    float* out_z    = (float*)d_out;
    float* out_xhat = out_z + (size_t)NN * 64;

    ushort_t* meanx = (ushort_t*)out_xhat;   // dead before xhat written
    float*    rbuf  = out_z;                 // r written here, z computed IN PLACE

    k_stage1<<<NBK + CVTB + PREPB, 256, 0, stream>>>(ei, px, pW1l, pW1r, pW2l, pW2r, pWd, pb1, pb2, pbd,
                                                     cntm, xb, wt, w2lt, w2rt, wdt, b1f, b2f, bdf);

    k_scanMA<<<MSB, 256, 0, stream>>>(cntm, offm, bsM);
    k_scatterC<<<NBK, 256, 0, stream>>>(ei, offm, bsM, pairs);
    k_d12<<<NBUK, 256, 0, stream>>>(pairs, offm, bsM, rowptr, srclist);

    int ab = (NN + 3) / 4;
    k_agg128<<<ab, 256, 0, stream>>>(xb, rowptr, srclist, meanx);

    k_gemm12<<<512, 256, 0, stream>>>(meanx, xb, wt, b1f, w2lt, w2rt, b2f, y, rbuf);
    k_agg2g3<<<NN / 16, 256, 0, stream>>>(y, rowptr, srclist, rbuf, wdt, bdf, out_xhat);
}